// Round 8
// baseline (224.465 us; speedup 1.0000x reference)
//
#include <hip/hip_runtime.h>
#include <hip/hip_bf16.h>

#define HEADS   16
#define GROUPS  4
#define C_IN    1024
#define C_OUT   1024
#define BATCH   4
#define SEQ     1024
#define DHEAD   64
#define DPG     256
#define MROWS   (BATCH * SEQ)   // 4096
#define NBH     (BATCH * HEADS) // 64
#define W_ELEMS ((size_t)GROUPS * DPG * DPG)   // 262144
#define N_ELEMS ((size_t)NBH * SEQ * DHEAD)    // 4194304

typedef short  bhalf8  __attribute__((ext_vector_type(8)));
typedef short  short4v __attribute__((ext_vector_type(4)));
typedef float  f32x4   __attribute__((ext_vector_type(4)));
typedef unsigned short ushort8v __attribute__((ext_vector_type(8)));

#define MFMA16 __builtin_amdgcn_mfma_f32_16x16x32_bf16

// hardware RNE f32 -> bf16 (compiler emits v_cvt_pk_bf16_f32 for pairs)
__device__ __forceinline__ unsigned short f2bf(float x) {
    union { __hip_bfloat16 b; unsigned short u; } c;
    c.b = __float2bfloat16(x);
    return c.u;
}
__device__ __forceinline__ float bf2f(unsigned short s) {
    return __uint_as_float(((unsigned int)s) << 16);
}

// ---------------------------------------------------------------------------
// Weight transpose+split: w[g][k][o] f32 -> wt{h,l}[g][o][k] bf16.
// grid (4 k-tiles, 4 o-tiles, 12 = which*4+g), one launch for all 3 weights.
// ---------------------------------------------------------------------------
__global__ void wsplit(const float* __restrict__ w0,
                       const float* __restrict__ w1,
                       const float* __restrict__ w2,
                       unsigned short* __restrict__ wtbase)
{
    const int tid = threadIdx.x;
    const int kt = blockIdx.x, ot = blockIdx.y;
    const int which = blockIdx.z >> 2, g = blockIdx.z & 3;
    const float* w = (which == 0) ? w0 : (which == 1) ? w1 : w2;
    unsigned short* wth = wtbase + (size_t)which * 2 * W_ELEMS;
    unsigned short* wtl = wth + W_ELEMS;

    __shared__ float Ls[64][68];
    const float* wg = w + (size_t)g * DPG * DPG;
#pragma unroll
    for (int p = 0; p < 4; ++p) {
        const int kk = 16 * p + (tid >> 4);
        const int oo = 4 * (tid & 15);
        const float4 v = *reinterpret_cast<const float4*>(
            wg + (size_t)(kt * 64 + kk) * DPG + ot * 64 + oo);
        Ls[kk][oo + 0] = v.x; Ls[kk][oo + 1] = v.y;
        Ls[kk][oo + 2] = v.z; Ls[kk][oo + 3] = v.w;
    }
    __syncthreads();
    unsigned short* th = wth + (size_t)g * DPG * DPG;
    unsigned short* tl = wtl + (size_t)g * DPG * DPG;
#pragma unroll
    for (int p = 0; p < 4; ++p) {
        const int oo = 16 * p + (tid >> 4);
        const int k4 = 4 * (tid & 15);
        ushort4 hv, lv;
        {
            float v0 = Ls[k4 + 0][oo], v1 = Ls[k4 + 1][oo];
            float v2 = Ls[k4 + 2][oo], v3 = Ls[k4 + 3][oo];
            hv.x = f2bf(v0); lv.x = f2bf(v0 - bf2f(hv.x));
            hv.y = f2bf(v1); lv.y = f2bf(v1 - bf2f(hv.y));
            hv.z = f2bf(v2); lv.z = f2bf(v2 - bf2f(hv.z));
            hv.w = f2bf(v3); lv.w = f2bf(v3 - bf2f(hv.w));
        }
        const size_t o = (size_t)(ot * 64 + oo) * DPG + kt * 64 + k4;
        *reinterpret_cast<ushort4*>(th + o) = hv;
        *reinterpret_cast<ushort4*>(tl + o) = lv;
    }
}

// ---------------------------------------------------------------------------
// Split-bf16 MFMA grouped projection, one launch for q,k,v.
// grid (64 m-tiles, 2 o-halves, 12 = which*4+g). Tile 64m x 128o, BK=64,
// 4 waves (2x2 quadrants of 32x64), 3-term split. Early-issue staging:
// next K-step's global loads are in regs while MFMA runs on current step.
// which 0 (query): outputs pre-scaled by 0.125 (exact).  which 2: V-transposed
// epilogue [bh][d][s]; else [bh][s][64].
// ---------------------------------------------------------------------------
__launch_bounds__(256, 2)
__global__ void proj_mfma(const float* __restrict__ xq,
                          const float* __restrict__ xk,
                          const float* __restrict__ xv,
                          const unsigned short* __restrict__ wtbase,
                          const float* __restrict__ bq,
                          const float* __restrict__ bk,
                          const float* __restrict__ bv,
                          unsigned short* __restrict__ outbase)
{
    const int tid  = threadIdx.x;
    const int wave = tid >> 6;
    const int lane = tid & 63;
    const int h    = lane >> 4;
    const int ln   = lane & 15;
    const int mq   = wave >> 1;
    const int nq   = wave & 1;
    const int bx   = blockIdx.x;
    const int by   = blockIdx.y;
    const int which = blockIdx.z >> 2, g = blockIdx.z & 3;
    const int m0   = bx * 64;

    const float* x    = (which == 0) ? xq : (which == 1) ? xk : xv;
    const float* bias = (which == 0) ? bq : (which == 1) ? bk : bv;
    unsigned short* outh = outbase + (size_t)which * 2 * N_ELEMS;
    unsigned short* outl = outh + N_ELEMS;

    __shared__ uint4 smem4[3072];        // 48 KB
    char* sp = (char*)smem4;             // Ah@0  Al@8192  Bh@16384  Bl@32768

    f32x4 acc[2][4];
#pragma unroll
    for (int a = 0; a < 2; ++a)
#pragma unroll
        for (int b = 0; b < 4; ++b) acc[a][b] = (f32x4){0.f, 0.f, 0.f, 0.f};

    const float* xg = x + (size_t)m0 * C_IN + g * DPG;
    const unsigned short* wh = wtbase + (size_t)which * 2 * W_ELEMS
                             + ((size_t)g * DPG + by * 128) * DPG;
    const unsigned short* wl = wh + W_ELEMS;

    // staging thread mapping
    const int arb = tid >> 4, ac = tid & 15;          // A: 16 rows x (k/4)
    const int brb = tid >> 3, bc = tid & 7;           // B: 32 rows x (k/8)

    float4   ar[4];
    ushort8v brh[4], brl[4];
    // preload k0 = 0
#pragma unroll
    for (int p = 0; p < 4; ++p)
        ar[p] = *reinterpret_cast<const float4*>(xg + (size_t)(16 * p + arb) * C_IN + 4 * ac);
#pragma unroll
    for (int p = 0; p < 4; ++p) {
        const size_t gofs = (size_t)(32 * p + brb) * DPG + 8 * bc;
        brh[p] = *reinterpret_cast<const ushort8v*>(wh + gofs);
        brl[p] = *reinterpret_cast<const ushort8v*>(wl + gofs);
    }

    for (int it = 0; it < 4; ++it) {
        if (it > 0) __syncthreads();     // prev compute reads done
        // ---- write staged regs -> LDS (A split here)
#pragma unroll
        for (int p = 0; p < 4; ++p) {
            const int rr = 16 * p + arb;
            const float4 v = ar[p];
            ushort4 hv, lv;
            hv.x = f2bf(v.x); lv.x = f2bf(v.x - bf2f(hv.x));
            hv.y = f2bf(v.y); lv.y = f2bf(v.y - bf2f(hv.y));
            hv.z = f2bf(v.z); lv.z = f2bf(v.z - bf2f(hv.z));
            hv.w = f2bf(v.w); lv.w = f2bf(v.w - bf2f(hv.w));
            const int off = (8 * ac) ^ ((rr & 7) << 4);
            *reinterpret_cast<ushort4*>(sp + rr * 128 + off) = hv;
            *reinterpret_cast<ushort4*>(sp + 8192 + rr * 128 + off) = lv;
        }
#pragma unroll
        for (int p = 0; p < 4; ++p) {
            const int rr = 32 * p + brb;
            const int off = (16 * bc) ^ ((rr & 7) << 4);
            *reinterpret_cast<ushort8v*>(sp + 16384 + rr * 128 + off) = brh[p];
            *reinterpret_cast<ushort8v*>(sp + 32768 + rr * 128 + off) = brl[p];
        }
        __syncthreads();

        // ---- issue next K-step loads (hidden under MFMA)
        if (it < 3) {
            const int k0n = (it + 1) * 64;
#pragma unroll
            for (int p = 0; p < 4; ++p)
                ar[p] = *reinterpret_cast<const float4*>(
                    xg + (size_t)(16 * p + arb) * C_IN + k0n + 4 * ac);
#pragma unroll
            for (int p = 0; p < 4; ++p) {
                const size_t gofs = (size_t)(32 * p + brb) * DPG + k0n + 8 * bc;
                brh[p] = *reinterpret_cast<const ushort8v*>(wh + gofs);
                brl[p] = *reinterpret_cast<const ushort8v*>(wl + gofs);
            }
        }

        // ---- MFMA: 2 kk x (2 mt x 4 nt) x 3 terms
#pragma unroll
        for (int kk = 0; kk < 2; ++kk) {
            bhalf8 ah[2], al[2], bh_[4], bl_[4];
#pragma unroll
            for (int mt = 0; mt < 2; ++mt) {
                const int row = 32 * mq + 16 * mt + ln;
                const int off = (64 * kk + 16 * h) ^ ((row & 7) << 4);
                ah[mt] = *reinterpret_cast<const bhalf8*>(sp + row * 128 + off);
                al[mt] = *reinterpret_cast<const bhalf8*>(sp + 8192 + row * 128 + off);
            }
#pragma unroll
            for (int nt = 0; nt < 4; ++nt) {
                const int row = 64 * nq + 16 * nt + ln;
                const int off = (64 * kk + 16 * h) ^ ((row & 7) << 4);
                bh_[nt] = *reinterpret_cast<const bhalf8*>(sp + 16384 + row * 128 + off);
                bl_[nt] = *reinterpret_cast<const bhalf8*>(sp + 32768 + row * 128 + off);
            }
#pragma unroll
            for (int mt = 0; mt < 2; ++mt)
#pragma unroll
                for (int nt = 0; nt < 4; ++nt) {
                    acc[mt][nt] = MFMA16(ah[mt], bh_[nt], acc[mt][nt], 0, 0, 0);
                    acc[mt][nt] = MFMA16(al[mt], bh_[nt], acc[mt][nt], 0, 0, 0);
                    acc[mt][nt] = MFMA16(ah[mt], bl_[nt], acc[mt][nt], 0, 0, 0);
                }
        }
    }
    __syncthreads();                     // all compute reads done; reuse LDS

    // ---- epilogue
    const int hd = g * 4 + by * 2 + nq;
    const int b  = bx >> 4;
    const size_t bhb = ((size_t)b * HEADS + hd) * (SEQ * DHEAD);
    const int wbase = wave * 8192;
    const int sg0 = (bx & 15) * 64 + 32 * mq;
    const float oscale = (which == 0) ? 0.125f : 1.0f;   // fold 1/sqrt(64) into q (exact)
    float bnt[4];
#pragma unroll
    for (int nt = 0; nt < 4; ++nt)
        bnt[nt] = bias[g * 256 + by * 128 + 64 * nq + 16 * nt + ln];

    if (which != 2) {
        // [32 s'][64 o'] ushort per wave, swizzled
#pragma unroll
        for (int mt = 0; mt < 2; ++mt)
#pragma unroll
            for (int nt = 0; nt < 4; ++nt)
#pragma unroll
                for (int r = 0; r < 4; ++r) {
                    const int sl = 16 * mt + 4 * h + r;
                    const float v = (acc[mt][nt][r] + bnt[nt]) * oscale;
                    const unsigned short hh = f2bf(v);
                    const unsigned short ll = f2bf(v - bf2f(hh));
                    const int cb = (2 * (16 * nt + ln)) ^ ((sl & 7) << 4);
                    *reinterpret_cast<unsigned short*>(sp + wbase + sl * 128 + cb) = hh;
                    *reinterpret_cast<unsigned short*>(sp + wbase + 4096 + sl * 128 + cb) = ll;
                }
        __syncthreads();
#pragma unroll
        for (int p = 0; p < 4; ++p) {
            const int sl = 8 * p + (lane >> 3);
            const int cb = (16 * (lane & 7)) ^ ((sl & 7) << 4);
            const size_t go = bhb + (size_t)(sg0 + sl) * 64 + 8 * (lane & 7);
            *reinterpret_cast<ushort8v*>(outh + go) =
                *reinterpret_cast<const ushort8v*>(sp + wbase + sl * 128 + cb);
            *reinterpret_cast<ushort8v*>(outl + go) =
                *reinterpret_cast<const ushort8v*>(sp + wbase + 4096 + sl * 128 + cb);
        }
    } else {
        // [64 d'][32 s'] ushort per wave, swizzled (8B granule)
#pragma unroll
        for (int mt = 0; mt < 2; ++mt)
#pragma unroll
            for (int nt = 0; nt < 4; ++nt) {
                const int dl = 16 * nt + ln;
                ushort4 hv, lv;
                {
                    float v0 = acc[mt][nt][0] + bnt[nt];
                    float v1 = acc[mt][nt][1] + bnt[nt];
                    float v2 = acc[mt][nt][2] + bnt[nt];
                    float v3 = acc[mt][nt][3] + bnt[nt];
                    hv.x = f2bf(v0); lv.x = f2bf(v0 - bf2f(hv.x));
                    hv.y = f2bf(v1); lv.y = f2bf(v1 - bf2f(hv.y));
                    hv.z = f2bf(v2); lv.z = f2bf(v2 - bf2f(hv.z));
                    hv.w = f2bf(v3); lv.w = f2bf(v3 - bf2f(hv.w));
                }
                const int off = (32 * mt + 8 * h) ^ ((dl & 7) << 3);
                *reinterpret_cast<ushort4*>(sp + wbase + dl * 64 + off) = hv;
                *reinterpret_cast<ushort4*>(sp + wbase + 4096 + dl * 64 + off) = lv;
            }
        __syncthreads();
#pragma unroll
        for (int p = 0; p < 4; ++p) {
            const int dl  = 16 * p + (lane >> 2);
            const int c16 = 16 * (lane & 3);
            const int o0b = (c16) ^ ((dl & 7) << 3);
            const int o1b = (c16 + 8) ^ ((dl & 7) << 3);
            const size_t go = bhb + (size_t)dl * SEQ + sg0 + 8 * (lane & 3);
            *reinterpret_cast<ushort4*>(outh + go) =
                *reinterpret_cast<const ushort4*>(sp + wbase + dl * 64 + o0b);
            *reinterpret_cast<ushort4*>(outh + go + 4) =
                *reinterpret_cast<const ushort4*>(sp + wbase + dl * 64 + o1b);
            *reinterpret_cast<ushort4*>(outl + go) =
                *reinterpret_cast<const ushort4*>(sp + wbase + 4096 + dl * 64 + o0b);
            *reinterpret_cast<ushort4*>(outl + go + 4) =
                *reinterpret_cast<const ushort4*>(sp + wbase + 4096 + dl * 64 + o1b);
        }
    }
}

// ---------------------------------------------------------------------------
// Split-bf16 MFMA flash attention.  Changes vs R4: grid = (bh, q-tile) so the
// 8 q-tiles sharing K/V co-locate on one XCD (id mod 8 = bh mod 8); staging
// loads early-issued into regs (latency hidden under MFMA); q pre-scaled in
// proj (no *0.125 here); P-split uses hw cvt.
// ---------------------------------------------------------------------------
__launch_bounds__(256, 2)
__global__ void attn_mfma(const unsigned short* __restrict__ qh,
                          const unsigned short* __restrict__ ql,
                          const unsigned short* __restrict__ kh,
                          const unsigned short* __restrict__ kl,
                          const unsigned short* __restrict__ vth,
                          const unsigned short* __restrict__ vtl,
                          float* __restrict__ out)   // [B,S,C_OUT]
{
    const int tid  = threadIdx.x;
    const int wave = tid >> 6;
    const int lane = tid & 63;
    const int h    = lane >> 4;
    const int ln   = lane & 15;
    const int bh   = blockIdx.x;                 // XCD co-location
    const int q0   = blockIdx.y * 128 + wave * 32;

    const size_t bhbase = (size_t)bh * (SEQ * DHEAD);
    const unsigned short* qhp = qh + bhbase;
    const unsigned short* qlp = ql + bhbase;
    const unsigned short* khp = kh + bhbase;
    const unsigned short* klp = kl + bhbase;
    const unsigned short* vhp = vth + bhbase;
    const unsigned short* vlp = vtl + bhbase;

    __shared__ uint4 smem4[2048];          // 32 KB: KH | KL | VH | VL
    char* sb = (char*)smem4;

    bhalf8 Qf[2][2][2];
#pragma unroll
    for (int nt = 0; nt < 2; ++nt)
#pragma unroll
        for (int dt = 0; dt < 2; ++dt) {
            const size_t o = (size_t)(q0 + 16 * nt + ln) * DHEAD + dt * 32 + 8 * h;
            Qf[nt][dt][0] = *reinterpret_cast<const bhalf8*>(qhp + o);
            Qf[nt][dt][1] = *reinterpret_cast<const bhalf8*>(qlp + o);
        }

    f32x4 accO[2][4];
#pragma unroll
    for (int a = 0; a < 2; ++a)
#pragma unroll
        for (int b = 0; b < 4; ++b) accO[a][b] = (f32x4){0.f, 0.f, 0.f, 0.f};
    float m_i[2] = {0.f, 0.f};
    float l_i[2] = {1.f, 1.f};

    // staging addresses (constant over iterations)
    const int r = tid >> 2, c = tid & 3;
    const int swz = (r & 7) << 4;
    const int d0 = r * 128 + ((c * 32) ^ swz);
    const int d1 = r * 128 + ((c * 32 + 16) ^ swz);
    const size_t gKr = (size_t)r * DHEAD + c * 16;   // + k0*DHEAD
    const size_t gVr = (size_t)r * SEQ + c * 16;     // + k0

    uint4 pr[8];
    {
        // preload tile 0
        pr[0] = *reinterpret_cast<const uint4*>(khp + gKr);
        pr[1] = *reinterpret_cast<const uint4*>(khp + gKr + 8);
        pr[2] = *reinterpret_cast<const uint4*>(klp + gKr);
        pr[3] = *reinterpret_cast<const uint4*>(klp + gKr + 8);
        pr[4] = *reinterpret_cast<const uint4*>(vhp + gVr);
        pr[5] = *reinterpret_cast<const uint4*>(vhp + gVr + 8);
        pr[6] = *reinterpret_cast<const uint4*>(vlp + gVr);
        pr[7] = *reinterpret_cast<const uint4*>(vlp + gVr + 8);
    }

    for (int kt16 = 0; kt16 < 16; ++kt16) {
        if (kt16 > 0) __syncthreads();     // prev compute reads done
        *reinterpret_cast<uint4*>(sb + d0)         = pr[0];
        *reinterpret_cast<uint4*>(sb + d1)         = pr[1];
        *reinterpret_cast<uint4*>(sb + 8192 + d0)  = pr[2];
        *reinterpret_cast<uint4*>(sb + 8192 + d1)  = pr[3];
        *reinterpret_cast<uint4*>(sb + 16384 + d0) = pr[4];
        *reinterpret_cast<uint4*>(sb + 16384 + d1) = pr[5];
        *reinterpret_cast<uint4*>(sb + 24576 + d0) = pr[6];
        *reinterpret_cast<uint4*>(sb + 24576 + d1) = pr[7];
        __syncthreads();

        // ---- early-issue next tile's loads (hidden under compute)
        if (kt16 < 15) {
            const size_t gK = gKr + (size_t)(kt16 + 1) * 64 * DHEAD;
            const size_t gV = gVr + (size_t)(kt16 + 1) * 64;
            pr[0] = *reinterpret_cast<const uint4*>(khp + gK);
            pr[1] = *reinterpret_cast<const uint4*>(khp + gK + 8);
            pr[2] = *reinterpret_cast<const uint4*>(klp + gK);
            pr[3] = *reinterpret_cast<const uint4*>(klp + gK + 8);
            pr[4] = *reinterpret_cast<const uint4*>(vhp + gV);
            pr[5] = *reinterpret_cast<const uint4*>(vhp + gV + 8);
            pr[6] = *reinterpret_cast<const uint4*>(vlp + gV);
            pr[7] = *reinterpret_cast<const uint4*>(vlp + gV + 8);
        }

        // ---- S^T = K · Q^T (3-term split); scores arrive pre-scaled
        f32x4 s_[2][4];
#pragma unroll
        for (int a = 0; a < 2; ++a)
#pragma unroll
            for (int b = 0; b < 4; ++b) s_[a][b] = (f32x4){0.f, 0.f, 0.f, 0.f};
#pragma unroll
        for (int mt = 0; mt < 4; ++mt) {
            const int rr = 16 * mt + ln;
            const int sw = (rr & 7) << 4;
            const bhalf8 Ah0 = *reinterpret_cast<const bhalf8*>(sb + rr * 128 + ((16 * h) ^ sw));
            const bhalf8 Ah1 = *reinterpret_cast<const bhalf8*>(sb + rr * 128 + ((64 + 16 * h) ^ sw));
            const bhalf8 Al0 = *reinterpret_cast<const bhalf8*>(sb + 8192 + rr * 128 + ((16 * h) ^ sw));
            const bhalf8 Al1 = *reinterpret_cast<const bhalf8*>(sb + 8192 + rr * 128 + ((64 + 16 * h) ^ sw));
#pragma unroll
            for (int nt = 0; nt < 2; ++nt) {
                s_[nt][mt] = MFMA16(Ah0, Qf[nt][0][0], s_[nt][mt], 0, 0, 0);
                s_[nt][mt] = MFMA16(Ah1, Qf[nt][1][0], s_[nt][mt], 0, 0, 0);
                s_[nt][mt] = MFMA16(Ah0, Qf[nt][0][1], s_[nt][mt], 0, 0, 0);
                s_[nt][mt] = MFMA16(Ah1, Qf[nt][1][1], s_[nt][mt], 0, 0, 0);
                s_[nt][mt] = MFMA16(Al0, Qf[nt][0][0], s_[nt][mt], 0, 0, 0);
                s_[nt][mt] = MFMA16(Al1, Qf[nt][1][0], s_[nt][mt], 0, 0, 0);
            }
        }

        // ---- online restricted softmax (margin = phantom score 0)
        float Pv[2][4][4];
        bhalf8 Pfh[2][2], Pfl[2][2];
#pragma unroll
        for (int nt = 0; nt < 2; ++nt) {
            float mloc = -1e30f;
#pragma unroll
            for (int mt = 0; mt < 4; ++mt)
#pragma unroll
                for (int rr = 0; rr < 4; ++rr) {
                    const float v = s_[nt][mt][rr];
                    Pv[nt][mt][rr] = v;
                    mloc = fmaxf(mloc, v);
                }
            mloc = fmaxf(mloc, __shfl_xor(mloc, 16));
            mloc = fmaxf(mloc, __shfl_xor(mloc, 32));
            const float mn = fmaxf(m_i[nt], mloc);
            const float sf = __expf(m_i[nt] - mn);
            m_i[nt] = mn;
            float rs = 0.f;
#pragma unroll
            for (int mt = 0; mt < 4; ++mt)
#pragma unroll
                for (int rr = 0; rr < 4; ++rr) {
                    const float p = __expf(Pv[nt][mt][rr] - mn);
                    Pv[nt][mt][rr] = p;
                    rs += p;
                }
            rs += __shfl_xor(rs, 16);
            rs += __shfl_xor(rs, 32);
            l_i[nt] = l_i[nt] * sf + rs;
#pragma unroll
            for (int rr = 0; rr < 4; ++rr) {
                const float sf_b = __shfl(sf, 20 * h + rr);
#pragma unroll
                for (int ntd = 0; ntd < 4; ++ntd) accO[nt][ntd][rr] *= sf_b;
            }
#pragma unroll
            for (int kt = 0; kt < 2; ++kt) {
                bhalf8 fh, fl;
#pragma unroll
                for (int j = 0; j < 8; ++j) {
                    const float p = Pv[nt][2 * kt + (j >> 2)][j & 3];
                    const unsigned short hi = f2bf(p);
                    fh[j] = (short)hi;
                    fl[j] = (short)f2bf(p - bf2f(hi));
                }
                Pfh[nt][kt] = fh;
                Pfl[nt][kt] = fl;
            }
        }

        // ---- O += P · V (3-term split)
#pragma unroll
        for (int kt = 0; kt < 2; ++kt) {
#pragma unroll
            for (int ntd = 0; ntd < 4; ++ntd) {
                const int rr = 16 * ntd + ln;
                const int sw = (rr & 7) << 4;
                const int c0 = (64 * kt + 8 * h) ^ sw;
                const int c1 = (64 * kt + 32 + 8 * h) ^ sw;
                union { short4v q[2]; bhalf8 v; } ubh, ubl;
                ubh.q[0] = *reinterpret_cast<const short4v*>(sb + 16384 + rr * 128 + c0);
                ubh.q[1] = *reinterpret_cast<const short4v*>(sb + 16384 + rr * 128 + c1);
                ubl.q[0] = *reinterpret_cast<const short4v*>(sb + 24576 + rr * 128 + c0);
                ubl.q[1] = *reinterpret_cast<const short4v*>(sb + 24576 + rr * 128 + c1);
                const bhalf8 Bh = ubh.v;
                const bhalf8 Bl = ubl.v;
#pragma unroll
                for (int nt = 0; nt < 2; ++nt) {
                    accO[nt][ntd] = MFMA16(Pfh[nt][kt], Bh, accO[nt][ntd], 0, 0, 0);
                    accO[nt][ntd] = MFMA16(Pfh[nt][kt], Bl, accO[nt][ntd], 0, 0, 0);
                    accO[nt][ntd] = MFMA16(Pfl[nt][kt], Bh, accO[nt][ntd], 0, 0, 0);
                }
            }
        }
    }

    const int bB = bh >> 4;
    const int hd = bh & 15;
#pragma unroll
    for (int nt = 0; nt < 2; ++nt) {
        float linv[4];
#pragma unroll
        for (int rr = 0; rr < 4; ++rr) linv[rr] = 1.0f / __shfl(l_i[nt], 20 * h + rr);
#pragma unroll
        for (int rr = 0; rr < 4; ++rr) {
            const int q = q0 + 16 * nt + 4 * h + rr;
            float* orow = out + ((size_t)bB * SEQ + q) * C_OUT + hd * DHEAD + ln;
#pragma unroll
            for (int ntd = 0; ntd < 4; ++ntd)
                orow[16 * ntd] = accO[nt][ntd][rr] * linv[rr];
        }
    }
}

extern "C" void kernel_launch(void* const* d_in, const int* in_sizes, int n_in,
                              void* d_out, int out_size, void* d_ws, size_t ws_size,
                              hipStream_t stream) {
    const float* query = (const float*)d_in[0];
    const float* key   = (const float*)d_in[1];
    const float* value = (const float*)d_in[2];
    const float* wq    = (const float*)d_in[3];
    const float* bq    = (const float*)d_in[4];
    const float* wk    = (const float*)d_in[5];
    const float* bk    = (const float*)d_in[6];
    const float* wv    = (const float*)d_in[7];
    const float* bv    = (const float*)d_in[8];

    unsigned short* qkv = (unsigned short*)d_ws;     // qh,ql,kh,kl,vh,vl (6N)
    unsigned short* wts = qkv + 6 * N_ELEMS;         // wqh,wql,wkh,wkl,wvh,wvl (6W)

    dim3 blk(256);
    wsplit<<<dim3(4, 4, 12), blk, 0, stream>>>(wq, wk, wv, wts);
    proj_mfma<<<dim3(MROWS / 64, 2, 12), blk, 0, stream>>>(
        query, key, value, wts, bq, bk, bv, qkv);

    attn_mfma<<<dim3(NBH, SEQ / 128), blk, 0, stream>>>(
        qkv, qkv + N_ELEMS, qkv + 2 * N_ELEMS, qkv + 3 * N_ELEMS,
        qkv + 4 * N_ELEMS, qkv + 5 * N_ELEMS, (float*)d_out);
}

// Round 9
// 191.728 us; speedup vs baseline: 1.1708x; 1.1708x over previous
//
#include <hip/hip_runtime.h>
#include <hip/hip_bf16.h>

#define HEADS   16
#define GROUPS  4
#define C_IN    1024
#define C_OUT   1024
#define BATCH   4
#define SEQ     1024
#define DHEAD   64
#define DPG     256
#define MROWS   (BATCH * SEQ)   // 4096
#define NBH     (BATCH * HEADS) // 64
#define W_ELEMS ((size_t)GROUPS * DPG * DPG)   // 262144
#define N_ELEMS ((size_t)NBH * SEQ * DHEAD)    // 4194304

typedef short  bhalf8  __attribute__((ext_vector_type(8)));
typedef short  short4v __attribute__((ext_vector_type(4)));
typedef float  f32x4   __attribute__((ext_vector_type(4)));
typedef unsigned short ushort8v __attribute__((ext_vector_type(8)));

#define MFMA16 __builtin_amdgcn_mfma_f32_16x16x32_bf16

// hardware RNE f32 -> bf16
__device__ __forceinline__ unsigned short f2bf(float x) {
    union { __hip_bfloat16 b; unsigned short u; } c;
    c.b = __float2bfloat16(x);
    return c.u;
}
__device__ __forceinline__ float bf2f(unsigned short s) {
    return __uint_as_float(((unsigned int)s) << 16);
}

// global -> LDS direct DMA, 16B per lane, wave-uniform LDS base (CK-style AS cast)
__device__ __forceinline__ void gload16(const void* gsrc, void* lds) {
    __builtin_amdgcn_global_load_lds(
        (const __attribute__((address_space(1))) unsigned int*)(unsigned long long)(uintptr_t)gsrc,
        (__attribute__((address_space(3))) unsigned int*)(unsigned int)(uintptr_t)lds,
        16, 0, 0);
}

// ---------------------------------------------------------------------------
// Weight transpose+split: w[g][k][o] f32 -> wt{h,l}[g][o][k] bf16.  (unchanged)
// ---------------------------------------------------------------------------
__global__ void wsplit(const float* __restrict__ w0,
                       const float* __restrict__ w1,
                       const float* __restrict__ w2,
                       unsigned short* __restrict__ wtbase)
{
    const int tid = threadIdx.x;
    const int kt = blockIdx.x, ot = blockIdx.y;
    const int which = blockIdx.z >> 2, g = blockIdx.z & 3;
    const float* w = (which == 0) ? w0 : (which == 1) ? w1 : w2;
    unsigned short* wth = wtbase + (size_t)which * 2 * W_ELEMS;
    unsigned short* wtl = wth + W_ELEMS;

    __shared__ float Ls[64][68];
    const float* wg = w + (size_t)g * DPG * DPG;
#pragma unroll
    for (int p = 0; p < 4; ++p) {
        const int kk = 16 * p + (tid >> 4);
        const int oo = 4 * (tid & 15);
        const float4 v = *reinterpret_cast<const float4*>(
            wg + (size_t)(kt * 64 + kk) * DPG + ot * 64 + oo);
        Ls[kk][oo + 0] = v.x; Ls[kk][oo + 1] = v.y;
        Ls[kk][oo + 2] = v.z; Ls[kk][oo + 3] = v.w;
    }
    __syncthreads();
    unsigned short* th = wth + (size_t)g * DPG * DPG;
    unsigned short* tl = wtl + (size_t)g * DPG * DPG;
#pragma unroll
    for (int p = 0; p < 4; ++p) {
        const int oo = 16 * p + (tid >> 4);
        const int k4 = 4 * (tid & 15);
        ushort4 hv, lv;
        {
            float v0 = Ls[k4 + 0][oo], v1 = Ls[k4 + 1][oo];
            float v2 = Ls[k4 + 2][oo], v3 = Ls[k4 + 3][oo];
            hv.x = f2bf(v0); lv.x = f2bf(v0 - bf2f(hv.x));
            hv.y = f2bf(v1); lv.y = f2bf(v1 - bf2f(hv.y));
            hv.z = f2bf(v2); lv.z = f2bf(v2 - bf2f(hv.z));
            hv.w = f2bf(v3); lv.w = f2bf(v3 - bf2f(hv.w));
        }
        const size_t o = (size_t)(ot * 64 + oo) * DPG + kt * 64 + k4;
        *reinterpret_cast<ushort4*>(th + o) = hv;
        *reinterpret_cast<ushort4*>(tl + o) = lv;
    }
}

// ---------------------------------------------------------------------------
// Split-bf16 MFMA grouped projection.  B (pre-split weights) staged via
// global_load_lds DMA with pre-swizzled per-lane source addresses (LDS dest
// linear); the DMA flies while A does f32->split-bf16 cvt staging.  m97-style
// single-buffer, __syncthreads drains DMA+LDS writes.
// ---------------------------------------------------------------------------
__launch_bounds__(256, 2)
__global__ void proj_mfma(const float* __restrict__ xq,
                          const float* __restrict__ xk,
                          const float* __restrict__ xv,
                          const unsigned short* __restrict__ wtbase,
                          const float* __restrict__ bq,
                          const float* __restrict__ bk,
                          const float* __restrict__ bv,
                          unsigned short* __restrict__ outbase)
{
    const int tid  = threadIdx.x;
    const int wave = tid >> 6;
    const int lane = tid & 63;
    const int h    = lane >> 4;
    const int ln   = lane & 15;
    const int mq   = wave >> 1;
    const int nq   = wave & 1;
    const int bx   = blockIdx.x;
    const int by   = blockIdx.y;
    const int which = blockIdx.z >> 2, g = blockIdx.z & 3;
    const int m0   = bx * 64;

    const float* x    = (which == 0) ? xq : (which == 1) ? xk : xv;
    const float* bias = (which == 0) ? bq : (which == 1) ? bk : bv;
    unsigned short* outh = outbase + (size_t)which * 2 * N_ELEMS;
    unsigned short* outl = outh + N_ELEMS;

    __shared__ uint4 smem4[3072];        // 48 KB
    char* sp = (char*)smem4;             // Ah@0  Al@8192  Bh@16384  Bl@32768

    f32x4 acc[2][4];
#pragma unroll
    for (int a = 0; a < 2; ++a)
#pragma unroll
        for (int b = 0; b < 4; ++b) acc[a][b] = (f32x4){0.f, 0.f, 0.f, 0.f};

    const float* xg = x + (size_t)m0 * C_IN + g * DPG;
    const unsigned short* wh = wtbase + (size_t)which * 2 * W_ELEMS
                             + ((size_t)g * DPG + by * 128) * DPG;
    const unsigned short* wl = wh + W_ELEMS;

    // ---- B DMA precompute: lds linear offset o -> (row, k) with swizzle
    // folded into the global source:  k = ((o&127) ^ ((row&7)<<4))/2
    int b_goff[4], b_lds[4];
#pragma unroll
    for (int c = 0; c < 4; ++c) {
        const int o  = (c * 4 + wave) * 1024 + lane * 16;
        const int rw = o >> 7;                       // 0..127 (o-row)
        const int kidx = ((o & 127) ^ ((rw & 7) << 4)) >> 1;
        b_goff[c] = rw * DPG + kidx;
        b_lds[c]  = (c * 4 + wave) * 1024;           // wave-uniform
    }

    // A staging mapping
    const int arb = tid >> 4, ac = tid & 15;         // 16 rows x (k/4)

    for (int it = 0; it < 4; ++it) {
        const int k0 = it * 64;
        if (it > 0) __syncthreads();     // prev compute reads done
        // ---- issue B DMA (flies under A's cvt work)
#pragma unroll
        for (int c = 0; c < 4; ++c) {
            gload16(wh + b_goff[c] + k0, sp + 16384 + b_lds[c]);
            gload16(wl + b_goff[c] + k0, sp + 32768 + b_lds[c]);
        }
        // ---- stage A: load f32, split, swizzled LDS write
#pragma unroll
        for (int p = 0; p < 4; ++p) {
            const int rr = 16 * p + arb;
            const float4 v = *reinterpret_cast<const float4*>(
                xg + (size_t)rr * C_IN + k0 + 4 * ac);
            ushort4 hv, lv;
            hv.x = f2bf(v.x); lv.x = f2bf(v.x - bf2f(hv.x));
            hv.y = f2bf(v.y); lv.y = f2bf(v.y - bf2f(hv.y));
            hv.z = f2bf(v.z); lv.z = f2bf(v.z - bf2f(hv.z));
            hv.w = f2bf(v.w); lv.w = f2bf(v.w - bf2f(hv.w));
            const int off = (8 * ac) ^ ((rr & 7) << 4);
            *reinterpret_cast<ushort4*>(sp + rr * 128 + off) = hv;
            *reinterpret_cast<ushort4*>(sp + 8192 + rr * 128 + off) = lv;
        }
        __syncthreads();                 // drains A writes + B DMA (vmcnt0)

        // ---- MFMA: 2 kk x (2 mt x 4 nt) x 3 terms
#pragma unroll
        for (int kk = 0; kk < 2; ++kk) {
            bhalf8 ah[2], al[2], bh_[4], bl_[4];
#pragma unroll
            for (int mt = 0; mt < 2; ++mt) {
                const int row = 32 * mq + 16 * mt + ln;
                const int off = (64 * kk + 16 * h) ^ ((row & 7) << 4);
                ah[mt] = *reinterpret_cast<const bhalf8*>(sp + row * 128 + off);
                al[mt] = *reinterpret_cast<const bhalf8*>(sp + 8192 + row * 128 + off);
            }
#pragma unroll
            for (int nt = 0; nt < 4; ++nt) {
                const int row = 64 * nq + 16 * nt + ln;
                const int off = (64 * kk + 16 * h) ^ ((row & 7) << 4);
                bh_[nt] = *reinterpret_cast<const bhalf8*>(sp + 16384 + row * 128 + off);
                bl_[nt] = *reinterpret_cast<const bhalf8*>(sp + 32768 + row * 128 + off);
            }
#pragma unroll
            for (int mt = 0; mt < 2; ++mt)
#pragma unroll
                for (int nt = 0; nt < 4; ++nt) {
                    acc[mt][nt] = MFMA16(ah[mt], bh_[nt], acc[mt][nt], 0, 0, 0);
                    acc[mt][nt] = MFMA16(al[mt], bh_[nt], acc[mt][nt], 0, 0, 0);
                    acc[mt][nt] = MFMA16(ah[mt], bl_[nt], acc[mt][nt], 0, 0, 0);
                }
        }
    }
    __syncthreads();                     // all compute reads done; reuse LDS

    // ---- epilogue (unchanged)
    const int hd = g * 4 + by * 2 + nq;
    const int b  = bx >> 4;
    const size_t bhb = ((size_t)b * HEADS + hd) * (SEQ * DHEAD);
    const int wbase = wave * 8192;
    const int sg0 = (bx & 15) * 64 + 32 * mq;
    const float oscale = (which == 0) ? 0.125f : 1.0f;
    float bnt[4];
#pragma unroll
    for (int nt = 0; nt < 4; ++nt)
        bnt[nt] = bias[g * 256 + by * 128 + 64 * nq + 16 * nt + ln];

    if (which != 2) {
#pragma unroll
        for (int mt = 0; mt < 2; ++mt)
#pragma unroll
            for (int nt = 0; nt < 4; ++nt)
#pragma unroll
                for (int r = 0; r < 4; ++r) {
                    const int sl = 16 * mt + 4 * h + r;
                    const float v = (acc[mt][nt][r] + bnt[nt]) * oscale;
                    const unsigned short hh = f2bf(v);
                    const unsigned short ll = f2bf(v - bf2f(hh));
                    const int cb = (2 * (16 * nt + ln)) ^ ((sl & 7) << 4);
                    *reinterpret_cast<unsigned short*>(sp + wbase + sl * 128 + cb) = hh;
                    *reinterpret_cast<unsigned short*>(sp + wbase + 4096 + sl * 128 + cb) = ll;
                }
        __syncthreads();
#pragma unroll
        for (int p = 0; p < 4; ++p) {
            const int sl = 8 * p + (lane >> 3);
            const int cb = (16 * (lane & 7)) ^ ((sl & 7) << 4);
            const size_t go = bhb + (size_t)(sg0 + sl) * 64 + 8 * (lane & 7);
            *reinterpret_cast<ushort8v*>(outh + go) =
                *reinterpret_cast<const ushort8v*>(sp + wbase + sl * 128 + cb);
            *reinterpret_cast<ushort8v*>(outl + go) =
                *reinterpret_cast<const ushort8v*>(sp + wbase + 4096 + sl * 128 + cb);
        }
    } else {
#pragma unroll
        for (int mt = 0; mt < 2; ++mt)
#pragma unroll
            for (int nt = 0; nt < 4; ++nt) {
                const int dl = 16 * nt + ln;
                ushort4 hv, lv;
                {
                    float v0 = acc[mt][nt][0] + bnt[nt];
                    float v1 = acc[mt][nt][1] + bnt[nt];
                    float v2 = acc[mt][nt][2] + bnt[nt];
                    float v3 = acc[mt][nt][3] + bnt[nt];
                    hv.x = f2bf(v0); lv.x = f2bf(v0 - bf2f(hv.x));
                    hv.y = f2bf(v1); lv.y = f2bf(v1 - bf2f(hv.y));
                    hv.z = f2bf(v2); lv.z = f2bf(v2 - bf2f(hv.z));
                    hv.w = f2bf(v3); lv.w = f2bf(v3 - bf2f(hv.w));
                }
                const int off = (32 * mt + 8 * h) ^ ((dl & 7) << 3);
                *reinterpret_cast<ushort4*>(sp + wbase + dl * 64 + off) = hv;
                *reinterpret_cast<ushort4*>(sp + wbase + 4096 + dl * 64 + off) = lv;
            }
        __syncthreads();
#pragma unroll
        for (int p = 0; p < 4; ++p) {
            const int dl  = 16 * p + (lane >> 2);
            const int c16 = 16 * (lane & 3);
            const int o0b = (c16) ^ ((dl & 7) << 3);
            const int o1b = (c16 + 8) ^ ((dl & 7) << 3);
            const size_t go = bhb + (size_t)dl * SEQ + sg0 + 8 * (lane & 3);
            *reinterpret_cast<ushort4*>(outh + go) =
                *reinterpret_cast<const ushort4*>(sp + wbase + dl * 64 + o0b);
            *reinterpret_cast<ushort4*>(outh + go + 4) =
                *reinterpret_cast<const ushort4*>(sp + wbase + dl * 64 + o1b);
            *reinterpret_cast<ushort4*>(outl + go) =
                *reinterpret_cast<const ushort4*>(sp + wbase + 4096 + dl * 64 + o0b);
            *reinterpret_cast<ushort4*>(outl + go + 4) =
                *reinterpret_cast<const ushort4*>(sp + wbase + 4096 + dl * 64 + o1b);
        }
    }
}

// ---------------------------------------------------------------------------
// Split-bf16 MFMA flash attention.  Double-buffered (2x32KB) K/V staging via
// global_load_lds DMA with pre-swizzled global sources; counted vmcnt(8) +
// raw s_barriers keep next tile's 8 loads in flight across the compute.
// Race-safety: writes of tile t+2 (into buf[t&1]) are only issued after
// bar2(t), which every wave passes only after its reads of buf[t&1] are done.
// ---------------------------------------------------------------------------
__launch_bounds__(256, 2)
__global__ void attn_mfma(const unsigned short* __restrict__ qh,
                          const unsigned short* __restrict__ ql,
                          const unsigned short* __restrict__ kh,
                          const unsigned short* __restrict__ kl,
                          const unsigned short* __restrict__ vth,
                          const unsigned short* __restrict__ vtl,
                          float* __restrict__ out)   // [B,S,C_OUT]
{
    const int tid  = threadIdx.x;
    const int wave = tid >> 6;
    const int lane = tid & 63;
    const int h    = lane >> 4;
    const int ln   = lane & 15;
    const int bh   = blockIdx.x;                 // XCD co-location
    const int q0   = blockIdx.y * 128 + wave * 32;

    const size_t bhbase = (size_t)bh * (SEQ * DHEAD);
    const unsigned short* qhp = qh + bhbase;
    const unsigned short* qlp = ql + bhbase;
    const unsigned short* khp = kh + bhbase;
    const unsigned short* klp = kl + bhbase;
    const unsigned short* vhp = vth + bhbase;
    const unsigned short* vlp = vtl + bhbase;

    __shared__ uint4 smem4[4096];          // 64 KB = 2 x (KH|KL|VH|VL)
    char* sb = (char*)smem4;

    bhalf8 Qf[2][2][2];
#pragma unroll
    for (int nt = 0; nt < 2; ++nt)
#pragma unroll
        for (int dt = 0; dt < 2; ++dt) {
            const size_t o = (size_t)(q0 + 16 * nt + ln) * DHEAD + dt * 32 + 8 * h;
            Qf[nt][dt][0] = *reinterpret_cast<const bhalf8*>(qhp + o);
            Qf[nt][dt][1] = *reinterpret_cast<const bhalf8*>(qlp + o);
        }

    f32x4 accO[2][4];
#pragma unroll
    for (int a = 0; a < 2; ++a)
#pragma unroll
        for (int b = 0; b < 4; ++b) accO[a][b] = (f32x4){0.f, 0.f, 0.f, 0.f};
    float m_i[2] = {0.f, 0.f};
    float l_i[2] = {1.f, 1.f};

    // ---- DMA precompute: 2 calls/buffer/thread; lds linear, source swizzled
    int rw_[2], kd_[2], lofs_[2];
#pragma unroll
    for (int c = 0; c < 2; ++c) {
        const int o = (c * 4 + wave) * 1024 + lane * 16;
        rw_[c]   = o >> 7;                                   // 0..63
        kd_[c]   = ((o & 127) ^ ((rw_[c] & 7) << 4)) >> 1;   // 0..63
        lofs_[c] = (c * 4 + wave) * 1024;                    // wave-uniform
    }

#define STAGE_TILE(BUF, K0)                                                        \
    do {                                                                           \
        _Pragma("unroll")                                                          \
        for (int c = 0; c < 2; ++c) {                                              \
            char* lb = sb + (BUF) + lofs_[c];                                      \
            const int rw = rw_[c], kd = kd_[c];                                    \
            gload16(khp + (size_t)((K0) + rw) * DHEAD + kd, lb);                   \
            gload16(klp + (size_t)((K0) + rw) * DHEAD + kd, lb + 8192);            \
            gload16(vhp + (size_t)rw * SEQ + (K0) + kd,     lb + 16384);           \
            gload16(vlp + (size_t)rw * SEQ + (K0) + kd,     lb + 24576);           \
        }                                                                          \
    } while (0)

    STAGE_TILE(0, 0);                      // prologue: tile 0 -> buf0

    for (int t = 0; t < 16; ++t) {
        const int nb = ((t + 1) & 1) * 32768;
        const int nk = ((t + 1) & 15) * 64;          // t=15 wraps (harmless dup)
        STAGE_TILE(nb, nk);
        // wait tile t's 8 loads (8 newest = tile t+1 stay in flight), sync
        asm volatile("s_waitcnt vmcnt(8)\n\ts_barrier" ::: "memory");

        const char* cb = sb + (t & 1) * 32768;

        // ---- S^T = K · Q^T (3-term split); scores pre-scaled via q
        f32x4 s_[2][4];
#pragma unroll
        for (int a = 0; a < 2; ++a)
#pragma unroll
            for (int b = 0; b < 4; ++b) s_[a][b] = (f32x4){0.f, 0.f, 0.f, 0.f};
#pragma unroll
        for (int mt = 0; mt < 4; ++mt) {
            const int rr = 16 * mt + ln;
            const int sw = (rr & 7) << 4;
            const bhalf8 Ah0 = *reinterpret_cast<const bhalf8*>(cb + rr * 128 + ((16 * h) ^ sw));
            const bhalf8 Ah1 = *reinterpret_cast<const bhalf8*>(cb + rr * 128 + ((64 + 16 * h) ^ sw));
            const bhalf8 Al0 = *reinterpret_cast<const bhalf8*>(cb + 8192 + rr * 128 + ((16 * h) ^ sw));
            const bhalf8 Al1 = *reinterpret_cast<const bhalf8*>(cb + 8192 + rr * 128 + ((64 + 16 * h) ^ sw));
#pragma unroll
            for (int nt = 0; nt < 2; ++nt) {
                s_[nt][mt] = MFMA16(Ah0, Qf[nt][0][0], s_[nt][mt], 0, 0, 0);
                s_[nt][mt] = MFMA16(Ah1, Qf[nt][1][0], s_[nt][mt], 0, 0, 0);
                s_[nt][mt] = MFMA16(Ah0, Qf[nt][0][1], s_[nt][mt], 0, 0, 0);
                s_[nt][mt] = MFMA16(Ah1, Qf[nt][1][1], s_[nt][mt], 0, 0, 0);
                s_[nt][mt] = MFMA16(Al0, Qf[nt][0][0], s_[nt][mt], 0, 0, 0);
                s_[nt][mt] = MFMA16(Al1, Qf[nt][1][0], s_[nt][mt], 0, 0, 0);
            }
        }

        // ---- online restricted softmax (margin = phantom score 0)
        float Pv[2][4][4];
        bhalf8 Pfh[2][2], Pfl[2][2];
#pragma unroll
        for (int nt = 0; nt < 2; ++nt) {
            float mloc = -1e30f;
#pragma unroll
            for (int mt = 0; mt < 4; ++mt)
#pragma unroll
                for (int rr = 0; rr < 4; ++rr) {
                    const float v = s_[nt][mt][rr];
                    Pv[nt][mt][rr] = v;
                    mloc = fmaxf(mloc, v);
                }
            mloc = fmaxf(mloc, __shfl_xor(mloc, 16));
            mloc = fmaxf(mloc, __shfl_xor(mloc, 32));
            const float mn = fmaxf(m_i[nt], mloc);
            const float sf = __expf(m_i[nt] - mn);
            m_i[nt] = mn;
            float rs = 0.f;
#pragma unroll
            for (int mt = 0; mt < 4; ++mt)
#pragma unroll
                for (int rr = 0; rr < 4; ++rr) {
                    const float p = __expf(Pv[nt][mt][rr] - mn);
                    Pv[nt][mt][rr] = p;
                    rs += p;
                }
            rs += __shfl_xor(rs, 16);
            rs += __shfl_xor(rs, 32);
            l_i[nt] = l_i[nt] * sf + rs;
#pragma unroll
            for (int rr = 0; rr < 4; ++rr) {
                const float sf_b = __shfl(sf, 20 * h + rr);
#pragma unroll
                for (int ntd = 0; ntd < 4; ++ntd) accO[nt][ntd][rr] *= sf_b;
            }
#pragma unroll
            for (int kt = 0; kt < 2; ++kt) {
                bhalf8 fh, fl;
#pragma unroll
                for (int j = 0; j < 8; ++j) {
                    const float p = Pv[nt][2 * kt + (j >> 2)][j & 3];
                    const unsigned short hi = f2bf(p);
                    fh[j] = (short)hi;
                    fl[j] = (short)f2bf(p - bf2f(hi));
                }
                Pfh[nt][kt] = fh;
                Pfl[nt][kt] = fl;
            }
        }

        // ---- O += P · V (3-term split)
#pragma unroll
        for (int kt = 0; kt < 2; ++kt) {
#pragma unroll
            for (int ntd = 0; ntd < 4; ++ntd) {
                const int rr = 16 * ntd + ln;
                const int sw = (rr & 7) << 4;
                const int c0 = (64 * kt + 8 * h) ^ sw;
                const int c1 = (64 * kt + 32 + 8 * h) ^ sw;
                union { short4v q[2]; bhalf8 v; } ubh, ubl;
                ubh.q[0] = *reinterpret_cast<const short4v*>(cb + 16384 + rr * 128 + c0);
                ubh.q[1] = *reinterpret_cast<const short4v*>(cb + 16384 + rr * 128 + c1);
                ubl.q[0] = *reinterpret_cast<const short4v*>(cb + 24576 + rr * 128 + c0);
                ubl.q[1] = *reinterpret_cast<const short4v*>(cb + 24576 + rr * 128 + c1);
                const bhalf8 Bh = ubh.v;
                const bhalf8 Bl = ubl.v;
#pragma unroll
                for (int nt = 0; nt < 2; ++nt) {
                    accO[nt][ntd] = MFMA16(Pfh[nt][kt], Bh, accO[nt][ntd], 0, 0, 0);
                    accO[nt][ntd] = MFMA16(Pfh[nt][kt], Bl, accO[nt][ntd], 0, 0, 0);
                    accO[nt][ntd] = MFMA16(Pfl[nt][kt], Bh, accO[nt][ntd], 0, 0, 0);
                }
            }
        }
        // reads of buf[t&1] done; release waves into next iter's STAGE
        asm volatile("s_barrier" ::: "memory");
    }
    asm volatile("s_waitcnt vmcnt(0)" ::: "memory");   // drain dangling wrap loads

    const int bB = bh >> 4;
    const int hd = bh & 15;
#pragma unroll
    for (int nt = 0; nt < 2; ++nt) {
        float linv[4];
#pragma unroll
        for (int rr = 0; rr < 4; ++rr) linv[rr] = 1.0f / __shfl(l_i[nt], 20 * h + rr);
#pragma unroll
        for (int rr = 0; rr < 4; ++rr) {
            const int q = q0 + 16 * nt + 4 * h + rr;
            float* orow = out + ((size_t)bB * SEQ + q) * C_OUT + hd * DHEAD + ln;
#pragma unroll
            for (int ntd = 0; ntd < 4; ++ntd)
                orow[16 * ntd] = accO[nt][ntd][rr] * linv[rr];
        }
    }
#undef STAGE_TILE
}

extern "C" void kernel_launch(void* const* d_in, const int* in_sizes, int n_in,
                              void* d_out, int out_size, void* d_ws, size_t ws_size,
                              hipStream_t stream) {
    const float* query = (const float*)d_in[0];
    const float* key   = (const float*)d_in[1];
    const float* value = (const float*)d_in[2];
    const float* wq    = (const float*)d_in[3];
    const float* bq    = (const float*)d_in[4];
    const float* wk    = (const float*)d_in[5];
    const float* bk    = (const float*)d_in[6];
    const float* wv    = (const float*)d_in[7];
    const float* bv    = (const float*)d_in[8];

    unsigned short* qkv = (unsigned short*)d_ws;     // qh,ql,kh,kl,vh,vl (6N)
    unsigned short* wts = qkv + 6 * N_ELEMS;         // wqh,wql,wkh,wkl,wvh,wvl (6W)

    dim3 blk(256);
    wsplit<<<dim3(4, 4, 12), blk, 0, stream>>>(wq, wk, wv, wts);
    proj_mfma<<<dim3(MROWS / 64, 2, 12), blk, 0, stream>>>(
        query, key, value, wts, bq, bk, bv, qkv);

    attn_mfma<<<dim3(NBH, SEQ / 128), blk, 0, stream>>>(
        qkv, qkv + N_ELEMS, qkv + 2 * N_ELEMS, qkv + 3 * N_ELEMS,
        qkv + 4 * N_ELEMS, qkv + 5 * N_ELEMS, (float*)d_out);
}

// Round 10
// 182.761 us; speedup vs baseline: 1.2282x; 1.0491x over previous
//
#include <hip/hip_runtime.h>
#include <hip/hip_bf16.h>

#define HEADS   16
#define GROUPS  4
#define C_IN    1024
#define C_OUT   1024
#define BATCH   4
#define SEQ     1024
#define DHEAD   64
#define DPG     256
#define MROWS   (BATCH * SEQ)   // 4096
#define NBH     (BATCH * HEADS) // 64
#define W_ELEMS ((size_t)GROUPS * DPG * DPG)   // 262144
#define N_ELEMS ((size_t)NBH * SEQ * DHEAD)    // 4194304

typedef short  bhalf8  __attribute__((ext_vector_type(8)));
typedef short  short4v __attribute__((ext_vector_type(4)));
typedef float  f32x4   __attribute__((ext_vector_type(4)));
typedef unsigned short ushort8v __attribute__((ext_vector_type(8)));

#define MFMA16 __builtin_amdgcn_mfma_f32_16x16x32_bf16

// hardware RNE f32 -> bf16
__device__ __forceinline__ unsigned short f2bf(float x) {
    union { __hip_bfloat16 b; unsigned short u; } c;
    c.b = __float2bfloat16(x);
    return c.u;
}
__device__ __forceinline__ float bf2f(unsigned short s) {
    return __uint_as_float(((unsigned int)s) << 16);
}
// raw v_exp_f32: D = 2^x (no libm fixup path)
__device__ __forceinline__ float exp2a(float x) {
    float r;
    asm("v_exp_f32 %0, %1" : "=v"(r) : "v"(x));
    return r;
}

// global -> LDS direct DMA, 16B per lane, wave-uniform LDS base
__device__ __forceinline__ void gload16(const void* gsrc, void* lds) {
    __builtin_amdgcn_global_load_lds(
        (const __attribute__((address_space(1))) unsigned int*)(unsigned long long)(uintptr_t)gsrc,
        (__attribute__((address_space(3))) unsigned int*)(unsigned int)(uintptr_t)lds,
        16, 0, 0);
}

// ---------------------------------------------------------------------------
// Weight transpose+split: w[g][k][o] f32 -> wt{h,l}[g][o][k] bf16. (unchanged)
// ---------------------------------------------------------------------------
__global__ void wsplit(const float* __restrict__ w0,
                       const float* __restrict__ w1,
                       const float* __restrict__ w2,
                       unsigned short* __restrict__ wtbase)
{
    const int tid = threadIdx.x;
    const int kt = blockIdx.x, ot = blockIdx.y;
    const int which = blockIdx.z >> 2, g = blockIdx.z & 3;
    const float* w = (which == 0) ? w0 : (which == 1) ? w1 : w2;
    unsigned short* wth = wtbase + (size_t)which * 2 * W_ELEMS;
    unsigned short* wtl = wth + W_ELEMS;

    __shared__ float Ls[64][68];
    const float* wg = w + (size_t)g * DPG * DPG;
#pragma unroll
    for (int p = 0; p < 4; ++p) {
        const int kk = 16 * p + (tid >> 4);
        const int oo = 4 * (tid & 15);
        const float4 v = *reinterpret_cast<const float4*>(
            wg + (size_t)(kt * 64 + kk) * DPG + ot * 64 + oo);
        Ls[kk][oo + 0] = v.x; Ls[kk][oo + 1] = v.y;
        Ls[kk][oo + 2] = v.z; Ls[kk][oo + 3] = v.w;
    }
    __syncthreads();
    unsigned short* th = wth + (size_t)g * DPG * DPG;
    unsigned short* tl = wtl + (size_t)g * DPG * DPG;
#pragma unroll
    for (int p = 0; p < 4; ++p) {
        const int oo = 16 * p + (tid >> 4);
        const int k4 = 4 * (tid & 15);
        ushort4 hv, lv;
        {
            float v0 = Ls[k4 + 0][oo], v1 = Ls[k4 + 1][oo];
            float v2 = Ls[k4 + 2][oo], v3 = Ls[k4 + 3][oo];
            hv.x = f2bf(v0); lv.x = f2bf(v0 - bf2f(hv.x));
            hv.y = f2bf(v1); lv.y = f2bf(v1 - bf2f(hv.y));
            hv.z = f2bf(v2); lv.z = f2bf(v2 - bf2f(hv.z));
            hv.w = f2bf(v3); lv.w = f2bf(v3 - bf2f(hv.w));
        }
        const size_t o = (size_t)(ot * 64 + oo) * DPG + kt * 64 + k4;
        *reinterpret_cast<ushort4*>(th + o) = hv;
        *reinterpret_cast<ushort4*>(tl + o) = lv;
    }
}

// ---------------------------------------------------------------------------
// Split-bf16 MFMA grouped projection (structure unchanged from R9).
// which 0 (query): outputs pre-scaled by 0.125*log2(e) so attention softmax
// can use raw v_exp_f32 (2^x) with no per-score multiply.
// ---------------------------------------------------------------------------
__launch_bounds__(256, 2)
__global__ void proj_mfma(const float* __restrict__ xq,
                          const float* __restrict__ xk,
                          const float* __restrict__ xv,
                          const unsigned short* __restrict__ wtbase,
                          const float* __restrict__ bq,
                          const float* __restrict__ bk,
                          const float* __restrict__ bv,
                          unsigned short* __restrict__ outbase)
{
    const int tid  = threadIdx.x;
    const int wave = tid >> 6;
    const int lane = tid & 63;
    const int h    = lane >> 4;
    const int ln   = lane & 15;
    const int mq   = wave >> 1;
    const int nq   = wave & 1;
    const int bx   = blockIdx.x;
    const int by   = blockIdx.y;
    const int which = blockIdx.z >> 2, g = blockIdx.z & 3;
    const int m0   = bx * 64;

    const float* x    = (which == 0) ? xq : (which == 1) ? xk : xv;
    const float* bias = (which == 0) ? bq : (which == 1) ? bk : bv;
    unsigned short* outh = outbase + (size_t)which * 2 * N_ELEMS;
    unsigned short* outl = outh + N_ELEMS;

    __shared__ uint4 smem4[3072];        // 48 KB
    char* sp = (char*)smem4;             // Ah@0  Al@8192  Bh@16384  Bl@32768

    f32x4 acc[2][4];
#pragma unroll
    for (int a = 0; a < 2; ++a)
#pragma unroll
        for (int b = 0; b < 4; ++b) acc[a][b] = (f32x4){0.f, 0.f, 0.f, 0.f};

    const float* xg = x + (size_t)m0 * C_IN + g * DPG;
    const unsigned short* wh = wtbase + (size_t)which * 2 * W_ELEMS
                             + ((size_t)g * DPG + by * 128) * DPG;
    const unsigned short* wl = wh + W_ELEMS;

    int b_goff[4], b_lds[4];
#pragma unroll
    for (int c = 0; c < 4; ++c) {
        const int o  = (c * 4 + wave) * 1024 + lane * 16;
        const int rw = o >> 7;
        const int kidx = ((o & 127) ^ ((rw & 7) << 4)) >> 1;
        b_goff[c] = rw * DPG + kidx;
        b_lds[c]  = (c * 4 + wave) * 1024;
    }

    const int arb = tid >> 4, ac = tid & 15;

    for (int it = 0; it < 4; ++it) {
        const int k0 = it * 64;
        if (it > 0) __syncthreads();
#pragma unroll
        for (int c = 0; c < 4; ++c) {
            gload16(wh + b_goff[c] + k0, sp + 16384 + b_lds[c]);
            gload16(wl + b_goff[c] + k0, sp + 32768 + b_lds[c]);
        }
#pragma unroll
        for (int p = 0; p < 4; ++p) {
            const int rr = 16 * p + arb;
            const float4 v = *reinterpret_cast<const float4*>(
                xg + (size_t)rr * C_IN + k0 + 4 * ac);
            ushort4 hv, lv;
            hv.x = f2bf(v.x); lv.x = f2bf(v.x - bf2f(hv.x));
            hv.y = f2bf(v.y); lv.y = f2bf(v.y - bf2f(hv.y));
            hv.z = f2bf(v.z); lv.z = f2bf(v.z - bf2f(hv.z));
            hv.w = f2bf(v.w); lv.w = f2bf(v.w - bf2f(hv.w));
            const int off = (8 * ac) ^ ((rr & 7) << 4);
            *reinterpret_cast<ushort4*>(sp + rr * 128 + off) = hv;
            *reinterpret_cast<ushort4*>(sp + 8192 + rr * 128 + off) = lv;
        }
        __syncthreads();

#pragma unroll
        for (int kk = 0; kk < 2; ++kk) {
            bhalf8 ah[2], al[2], bh_[4], bl_[4];
#pragma unroll
            for (int mt = 0; mt < 2; ++mt) {
                const int row = 32 * mq + 16 * mt + ln;
                const int off = (64 * kk + 16 * h) ^ ((row & 7) << 4);
                ah[mt] = *reinterpret_cast<const bhalf8*>(sp + row * 128 + off);
                al[mt] = *reinterpret_cast<const bhalf8*>(sp + 8192 + row * 128 + off);
            }
#pragma unroll
            for (int nt = 0; nt < 4; ++nt) {
                const int row = 64 * nq + 16 * nt + ln;
                const int off = (64 * kk + 16 * h) ^ ((row & 7) << 4);
                bh_[nt] = *reinterpret_cast<const bhalf8*>(sp + 16384 + row * 128 + off);
                bl_[nt] = *reinterpret_cast<const bhalf8*>(sp + 32768 + row * 128 + off);
            }
#pragma unroll
            for (int mt = 0; mt < 2; ++mt)
#pragma unroll
                for (int nt = 0; nt < 4; ++nt) {
                    acc[mt][nt] = MFMA16(ah[mt], bh_[nt], acc[mt][nt], 0, 0, 0);
                    acc[mt][nt] = MFMA16(al[mt], bh_[nt], acc[mt][nt], 0, 0, 0);
                    acc[mt][nt] = MFMA16(ah[mt], bl_[nt], acc[mt][nt], 0, 0, 0);
                }
        }
    }
    __syncthreads();

    // ---- epilogue
    const int hd = g * 4 + by * 2 + nq;
    const int b  = bx >> 4;
    const size_t bhb = ((size_t)b * HEADS + hd) * (SEQ * DHEAD);
    const int wbase = wave * 8192;
    const int sg0 = (bx & 15) * 64 + 32 * mq;
    // q: fold 1/sqrt(64) * log2(e) so softmax is raw 2^x
    const float oscale = (which == 0) ? 0.18033688011112042f : 1.0f;
    float bnt[4];
#pragma unroll
    for (int nt = 0; nt < 4; ++nt)
        bnt[nt] = bias[g * 256 + by * 128 + 64 * nq + 16 * nt + ln];

    if (which != 2) {
#pragma unroll
        for (int mt = 0; mt < 2; ++mt)
#pragma unroll
            for (int nt = 0; nt < 4; ++nt)
#pragma unroll
                for (int r = 0; r < 4; ++r) {
                    const int sl = 16 * mt + 4 * h + r;
                    const float v = (acc[mt][nt][r] + bnt[nt]) * oscale;
                    const unsigned short hh = f2bf(v);
                    const unsigned short ll = f2bf(v - bf2f(hh));
                    const int cb = (2 * (16 * nt + ln)) ^ ((sl & 7) << 4);
                    *reinterpret_cast<unsigned short*>(sp + wbase + sl * 128 + cb) = hh;
                    *reinterpret_cast<unsigned short*>(sp + wbase + 4096 + sl * 128 + cb) = ll;
                }
        __syncthreads();
#pragma unroll
        for (int p = 0; p < 4; ++p) {
            const int sl = 8 * p + (lane >> 3);
            const int cb = (16 * (lane & 7)) ^ ((sl & 7) << 4);
            const size_t go = bhb + (size_t)(sg0 + sl) * 64 + 8 * (lane & 7);
            *reinterpret_cast<ushort8v*>(outh + go) =
                *reinterpret_cast<const ushort8v*>(sp + wbase + sl * 128 + cb);
            *reinterpret_cast<ushort8v*>(outl + go) =
                *reinterpret_cast<const ushort8v*>(sp + wbase + 4096 + sl * 128 + cb);
        }
    } else {
#pragma unroll
        for (int mt = 0; mt < 2; ++mt)
#pragma unroll
            for (int nt = 0; nt < 4; ++nt) {
                const int dl = 16 * nt + ln;
                ushort4 hv, lv;
                {
                    float v0 = acc[mt][nt][0] + bnt[nt];
                    float v1 = acc[mt][nt][1] + bnt[nt];
                    float v2 = acc[mt][nt][2] + bnt[nt];
                    float v3 = acc[mt][nt][3] + bnt[nt];
                    hv.x = f2bf(v0); lv.x = f2bf(v0 - bf2f(hv.x));
                    hv.y = f2bf(v1); lv.y = f2bf(v1 - bf2f(hv.y));
                    hv.z = f2bf(v2); lv.z = f2bf(v2 - bf2f(hv.z));
                    hv.w = f2bf(v3); lv.w = f2bf(v3 - bf2f(hv.w));
                }
                const int off = (32 * mt + 8 * h) ^ ((dl & 7) << 3);
                *reinterpret_cast<ushort4*>(sp + wbase + dl * 64 + off) = hv;
                *reinterpret_cast<ushort4*>(sp + wbase + 4096 + dl * 64 + off) = lv;
            }
        __syncthreads();
#pragma unroll
        for (int p = 0; p < 4; ++p) {
            const int dl  = 16 * p + (lane >> 2);
            const int c16 = 16 * (lane & 3);
            const int o0b = (c16) ^ ((dl & 7) << 3);
            const int o1b = (c16 + 8) ^ ((dl & 7) << 3);
            const size_t go = bhb + (size_t)dl * SEQ + sg0 + 8 * (lane & 3);
            *reinterpret_cast<ushort4*>(outh + go) =
                *reinterpret_cast<const ushort4*>(sp + wbase + dl * 64 + o0b);
            *reinterpret_cast<ushort4*>(outh + go + 4) =
                *reinterpret_cast<const ushort4*>(sp + wbase + dl * 64 + o1b);
            *reinterpret_cast<ushort4*>(outl + go) =
                *reinterpret_cast<const ushort4*>(sp + wbase + 4096 + dl * 64 + o0b);
            *reinterpret_cast<ushort4*>(outl + go + 4) =
                *reinterpret_cast<const ushort4*>(sp + wbase + 4096 + dl * 64 + o1b);
        }
    }
}

// ---------------------------------------------------------------------------
// Split-bf16 MFMA flash attention.  Changes vs R9:
//  * LDS 48 KB (K double-buffered 2x16KB @0/16384; V single 16KB @32768)
//    -> 3 blocks/CU (12 waves/CU, was 8).
//  * 3-barrier schedule, counted vmcnt(8)/vmcnt(4): V(t)+K(t+1) DMA stay in
//    flight across QK^T; V(t) lands just before PV.
//  * softmax in log2 domain: q pre-scaled by 0.125*log2e, raw v_exp_f32,
//    defer-max (THR=10 log2 units) skips rescale when max doesn't grow.
// ---------------------------------------------------------------------------
__launch_bounds__(256, 3)
__global__ void attn_mfma(const unsigned short* __restrict__ qh,
                          const unsigned short* __restrict__ ql,
                          const unsigned short* __restrict__ kh,
                          const unsigned short* __restrict__ kl,
                          const unsigned short* __restrict__ vth,
                          const unsigned short* __restrict__ vtl,
                          float* __restrict__ out)   // [B,S,C_OUT]
{
    const int tid  = threadIdx.x;
    const int wave = tid >> 6;
    const int lane = tid & 63;
    const int h    = lane >> 4;
    const int ln   = lane & 15;
    const int bh   = blockIdx.x;                 // XCD co-location
    const int q0   = blockIdx.y * 128 + wave * 32;

    const size_t bhbase = (size_t)bh * (SEQ * DHEAD);
    const unsigned short* qhp = qh + bhbase;
    const unsigned short* qlp = ql + bhbase;
    const unsigned short* khp = kh + bhbase;
    const unsigned short* klp = kl + bhbase;
    const unsigned short* vhp = vth + bhbase;
    const unsigned short* vlp = vtl + bhbase;

    __shared__ uint4 smem4[3072];          // 48 KB
    char* sb = (char*)smem4;               // Kbuf0@0 Kbuf1@16384 V@32768

    bhalf8 Qf[2][2][2];
#pragma unroll
    for (int nt = 0; nt < 2; ++nt)
#pragma unroll
        for (int dt = 0; dt < 2; ++dt) {
            const size_t o = (size_t)(q0 + 16 * nt + ln) * DHEAD + dt * 32 + 8 * h;
            Qf[nt][dt][0] = *reinterpret_cast<const bhalf8*>(qhp + o);
            Qf[nt][dt][1] = *reinterpret_cast<const bhalf8*>(qlp + o);
        }

    f32x4 accO[2][4];
#pragma unroll
    for (int a = 0; a < 2; ++a)
#pragma unroll
        for (int b = 0; b < 4; ++b) accO[a][b] = (f32x4){0.f, 0.f, 0.f, 0.f};
    float m_i[2] = {0.f, 0.f};             // log2 units; margin phantom = 2^0
    float l_i[2] = {1.f, 1.f};

    // DMA mapping: 2 chunks per 8KB array per thread; lds linear, src swizzled
    int rw_[2], kd_[2], lofs_[2];
#pragma unroll
    for (int c = 0; c < 2; ++c) {
        const int o = (c * 4 + wave) * 1024 + lane * 16;
        rw_[c]   = o >> 7;
        kd_[c]   = ((o & 127) ^ ((rw_[c] & 7) << 4)) >> 1;
        lofs_[c] = (c * 4 + wave) * 1024;
    }

#define STAGE_K(BUF, K0)                                                       \
    do {                                                                       \
        _Pragma("unroll")                                                      \
        for (int c = 0; c < 2; ++c) {                                          \
            char* lb = sb + (BUF) + lofs_[c];                                  \
            gload16(khp + (size_t)((K0) + rw_[c]) * DHEAD + kd_[c], lb);       \
            gload16(klp + (size_t)((K0) + rw_[c]) * DHEAD + kd_[c], lb + 8192);\
        }                                                                      \
    } while (0)
#define STAGE_V(K0)                                                            \
    do {                                                                       \
        _Pragma("unroll")                                                      \
        for (int c = 0; c < 2; ++c) {                                          \
            char* lb = sb + 32768 + lofs_[c];                                  \
            gload16(vhp + (size_t)rw_[c] * SEQ + (K0) + kd_[c], lb);           \
            gload16(vlp + (size_t)rw_[c] * SEQ + (K0) + kd_[c], lb + 8192);    \
        }                                                                      \
    } while (0)

    STAGE_K(0, 0);                         // prologue: K(0) -> buf0  (4 loads)

    for (int t = 0; t < 16; ++t) {
        STAGE_V(t * 64);                                   // 4 loads
        STAGE_K(((t + 1) & 1) * 16384, ((t + 1) & 15) * 64); // 4 loads (t=15: dup)
        // wait K(t) (oldest 4); V(t)+K(t+1) (8 newest) stay in flight
        asm volatile("s_waitcnt vmcnt(8)\n\ts_barrier" ::: "memory");

        const char* cb = sb + (t & 1) * 16384;

        // ---- S'^T = K · Q'^T  (log2-scaled scores via q pre-scale)
        f32x4 s_[2][4];
#pragma unroll
        for (int a = 0; a < 2; ++a)
#pragma unroll
            for (int b = 0; b < 4; ++b) s_[a][b] = (f32x4){0.f, 0.f, 0.f, 0.f};
#pragma unroll
        for (int mt = 0; mt < 4; ++mt) {
            const int rr = 16 * mt + ln;
            const int sw = (rr & 7) << 4;
            const bhalf8 Ah0 = *reinterpret_cast<const bhalf8*>(cb + rr * 128 + ((16 * h) ^ sw));
            const bhalf8 Ah1 = *reinterpret_cast<const bhalf8*>(cb + rr * 128 + ((64 + 16 * h) ^ sw));
            const bhalf8 Al0 = *reinterpret_cast<const bhalf8*>(cb + 8192 + rr * 128 + ((16 * h) ^ sw));
            const bhalf8 Al1 = *reinterpret_cast<const bhalf8*>(cb + 8192 + rr * 128 + ((64 + 16 * h) ^ sw));
#pragma unroll
            for (int nt = 0; nt < 2; ++nt) {
                s_[nt][mt] = MFMA16(Ah0, Qf[nt][0][0], s_[nt][mt], 0, 0, 0);
                s_[nt][mt] = MFMA16(Ah1, Qf[nt][1][0], s_[nt][mt], 0, 0, 0);
                s_[nt][mt] = MFMA16(Ah0, Qf[nt][0][1], s_[nt][mt], 0, 0, 0);
                s_[nt][mt] = MFMA16(Ah1, Qf[nt][1][1], s_[nt][mt], 0, 0, 0);
                s_[nt][mt] = MFMA16(Al0, Qf[nt][0][0], s_[nt][mt], 0, 0, 0);
                s_[nt][mt] = MFMA16(Al1, Qf[nt][1][0], s_[nt][mt], 0, 0, 0);
            }
        }

        // ---- online restricted softmax in log2 domain, defer-max
        float Pv[2][4][4];
        bhalf8 Pfh[2][2], Pfl[2][2];
#pragma unroll
        for (int nt = 0; nt < 2; ++nt) {
            float mloc = -1e30f;
#pragma unroll
            for (int mt = 0; mt < 4; ++mt)
#pragma unroll
                for (int rr = 0; rr < 4; ++rr) {
                    const float v = s_[nt][mt][rr];
                    Pv[nt][mt][rr] = v;
                    mloc = fmaxf(mloc, v);
                }
            mloc = fmaxf(mloc, __shfl_xor(mloc, 16));
            mloc = fmaxf(mloc, __shfl_xor(mloc, 32));
            // defer-max: rescale only if some column's max grew past THR
            if (__any(mloc > m_i[nt] + 10.0f)) {
                const float mn = fmaxf(m_i[nt], mloc);
                const float sf = exp2a(m_i[nt] - mn);
                m_i[nt] = mn;
                l_i[nt] *= sf;
#pragma unroll
                for (int rr = 0; rr < 4; ++rr) {
                    const float sf_b = __shfl(sf, 20 * h + rr);
#pragma unroll
                    for (int ntd = 0; ntd < 4; ++ntd) accO[nt][ntd][rr] *= sf_b;
                }
            }
            float rs = 0.f;
            const float mcur = m_i[nt];
#pragma unroll
            for (int mt = 0; mt < 4; ++mt)
#pragma unroll
                for (int rr = 0; rr < 4; ++rr) {
                    const float p = exp2a(Pv[nt][mt][rr] - mcur);
                    Pv[nt][mt][rr] = p;
                    rs += p;
                }
            rs += __shfl_xor(rs, 16);
            rs += __shfl_xor(rs, 32);
            l_i[nt] += rs;
#pragma unroll
            for (int kt = 0; kt < 2; ++kt) {
                bhalf8 fh, fl;
#pragma unroll
                for (int j = 0; j < 8; ++j) {
                    const float p = Pv[nt][2 * kt + (j >> 2)][j & 3];
                    const unsigned short hi = f2bf(p);
                    fh[j] = (short)hi;
                    fl[j] = (short)f2bf(p - bf2f(hi));
                }
                Pfh[nt][kt] = fh;
                Pfl[nt][kt] = fl;
            }
        }

        // V(t) ready (4 newest = K(t+1) still in flight); all waves synced
        asm volatile("s_waitcnt vmcnt(4)\n\ts_barrier" ::: "memory");

        // ---- O += P · V (3-term split), V from single buffer @32768
#pragma unroll
        for (int kt = 0; kt < 2; ++kt) {
#pragma unroll
            for (int ntd = 0; ntd < 4; ++ntd) {
                const int rr = 16 * ntd + ln;
                const int sw = (rr & 7) << 4;
                const int c0 = (64 * kt + 8 * h) ^ sw;
                const int c1 = (64 * kt + 32 + 8 * h) ^ sw;
                union { short4v q[2]; bhalf8 v; } ubh, ubl;
                ubh.q[0] = *reinterpret_cast<const short4v*>(sb + 32768 + rr * 128 + c0);
                ubh.q[1] = *reinterpret_cast<const short4v*>(sb + 32768 + rr * 128 + c1);
                ubl.q[0] = *reinterpret_cast<const short4v*>(sb + 40960 + rr * 128 + c0);
                ubl.q[1] = *reinterpret_cast<const short4v*>(sb + 40960 + rr * 128 + c1);
                const bhalf8 Bh = ubh.v;
                const bhalf8 Bl = ubl.v;
#pragma unroll
                for (int nt = 0; nt < 2; ++nt) {
                    accO[nt][ntd] = MFMA16(Pfh[nt][kt], Bh, accO[nt][ntd], 0, 0, 0);
                    accO[nt][ntd] = MFMA16(Pfh[nt][kt], Bl, accO[nt][ntd], 0, 0, 0);
                    accO[nt][ntd] = MFMA16(Pfl[nt][kt], Bh, accO[nt][ntd], 0, 0, 0);
                }
            }
        }
        // V reads done -> next iteration may overwrite V buffer
        asm volatile("s_barrier" ::: "memory");
    }
    asm volatile("s_waitcnt vmcnt(0)" ::: "memory");   // drain wrap-dup loads

    const int bB = bh >> 4;
    const int hd = bh & 15;
#pragma unroll
    for (int nt = 0; nt < 2; ++nt) {
        float linv[4];
#pragma unroll
        for (int rr = 0; rr < 4; ++rr) linv[rr] = 1.0f / __shfl(l_i[nt], 20 * h + rr);
#pragma unroll
        for (int rr = 0; rr < 4; ++rr) {
            const int q = q0 + 16 * nt + 4 * h + rr;
            float* orow = out + ((size_t)bB * SEQ + q) * C_OUT + hd * DHEAD + ln;
#pragma unroll
            for (int ntd = 0; ntd < 4; ++ntd)
                orow[16 * ntd] = accO[nt][ntd][rr] * linv[rr];
        }
    }
#undef STAGE_K
#undef STAGE_V
}

extern "C" void kernel_launch(void* const* d_in, const int* in_sizes, int n_in,
                              void* d_out, int out_size, void* d_ws, size_t ws_size,
                              hipStream_t stream) {
    const float* query = (const float*)d_in[0];
    const float* key   = (const float*)d_in[1];
    const float* value = (const float*)d_in[2];
    const float* wq    = (const float*)d_in[3];
    const float* bq    = (const float*)d_in[4];
    const float* wk    = (const float*)d_in[5];
    const float* bk    = (const float*)d_in[6];
    const float* wv    = (const float*)d_in[7];
    const float* bv    = (const float*)d_in[8];

    unsigned short* qkv = (unsigned short*)d_ws;     // qh,ql,kh,kl,vh,vl (6N)
    unsigned short* wts = qkv + 6 * N_ELEMS;         // wqh,wql,wkh,wkl,wvh,wvl (6W)

    dim3 blk(256);
    wsplit<<<dim3(4, 4, 12), blk, 0, stream>>>(wq, wk, wv, wts);
    proj_mfma<<<dim3(MROWS / 64, 2, 12), blk, 0, stream>>>(
        query, key, value, wts, bq, bk, bv, qkv);

    attn_mfma<<<dim3(NBH, SEQ / 128), blk, 0, stream>>>(
        qkv, qkv + N_ELEMS, qkv + 2 * N_ELEMS, qkv + 3 * N_ELEMS,
        qkv + 4 * N_ELEMS, qkv + 5 * N_ELEMS, (float*)d_out);
}